// Round 13
// baseline (436.373 us; speedup 1.0000x reference)
//
#include <hip/hip_runtime.h>
#include <hip/hip_cooperative_groups.h>
#include <stdint.h>

namespace cg = cooperative_groups;

#define N_TOTAL 21840
#define NA      21888          // N_TOTAL rounded up to multiple of 64
#define W_MAX   342            // ceil(21840/64)
#define TOT_ENT 3753792u       // 64 * (342*343/2)  triangular dense capacity
#define NMS_TH  0.3f
#define FINAL_TH 0.5f
#define NSLICE  8              // rank range-split factor
#define SCAN_T  768            // scan roles: 1 scanner wave + 11 pusher waves
#define NPUSH   11             // pusher wave count
#define PLANES  704            // NPUSH*64 pusher lanes
#define GRP     4              // words per scan group
#define NBAND   7              // 2*GRP-1 transposed band arrays
#define GMAX    86             // max groups = ceil(W_MAX/GRP)
#define FUSED_B 256            // fused grid: 1 block per CU (guaranteed resident)
#define FUSED_T 1024

struct Inputs { const float* cls[6]; const float* reg[6]; };

// Raw barrier: drains LDS (lgkmcnt) but NOT vmem (vmcnt).
__device__ __forceinline__ void block_bar() {
  asm volatile("s_waitcnt lgkmcnt(0)\n\ts_barrier" ::: "memory");
}

// Dense per-word base: word w owns 64*(342-w) entry slots (triangular).
__device__ __forceinline__ unsigned wbase_u(unsigned w) {
  return 64u * (342u * w - (w * (w - 1u)) / 2u);
}

// ================= FUSED cooperative kernel ==================================
// R12 post-mortem: the non-scan remainder is a CONSTANT ~163 µs across all 13
// rounds while estimated phase compute is ~25 µs — the bulk is fixed per-launch
// dispatch overhead x 5 dependent launches. Fuse everything into one
// cooperative kernel with grid.sync() between phases. Phase bodies are
// verbatim from the verified split kernels (R6 scan protocol, 99.4 µs).
__global__ void __launch_bounds__(FUSED_T, 4)
fused_kernel(Inputs in,
             float* __restrict__ dx1, float* __restrict__ dy1,
             float* __restrict__ dx2, float* __restrict__ dy2,
             float* __restrict__ dsc,
             unsigned long long* __restrict__ ckey,
             float* __restrict__ sx1, float* __restrict__ sy1,
             float* __restrict__ sx2, float* __restrict__ sy2,
             unsigned int* __restrict__ sorig,
             unsigned int* __restrict__ rank32,
             unsigned int* __restrict__ wcnt,
             unsigned int* __restrict__ Mc,
             unsigned long long* __restrict__ diag,
             unsigned long long* __restrict__ bandT,
             unsigned short* __restrict__ rlMeta,
             unsigned long long* __restrict__ rlBits,
             float* __restrict__ out) {
#pragma clang fp contract(off)
  cg::grid_group grid = cg::this_grid();
  __shared__ unsigned long long smem8[2592];   // 20736 B phase union

  const int tid = (int)threadIdx.x;
  const int bid = (int)blockIdx.x;
  const int gtid = bid * FUSED_T + tid;

  // ---- phase 0: zero Mc ----
  if (gtid < 16) Mc[gtid] = 0u;
  grid.sync();

  // ---- phase 1: decode (verbatim body, grid-stride) ----
  for (int gid = gtid; gid < N_TOTAL; gid += FUSED_B * FUSED_T) {
    rank32[gid] = 0u;
    wcnt[gid] = 0u;
    if (gid < NA - N_TOTAL) wcnt[N_TOTAL + gid] = 0u;

    int sc, local;
    if      (gid < 16384) { sc = 0; local = gid;         }
    else if (gid < 20480) { sc = 1; local = gid - 16384; }
    else if (gid < 21504) { sc = 2; local = gid - 20480; }
    else if (gid < 21760) { sc = 3; local = gid - 21504; }
    else if (gid < 21824) { sc = 4; local = gid - 21760; }
    else                  { sc = 5; local = gid - 21824; }

    const int Wd     = 128 >> sc;
    const int stride = 4 << sc;
    const int HW     = Wd * Wd;
    const int x = local & (Wd - 1);
    const int y = local >> (7 - sc);

    const float* cls = in.cls[sc];
    const float* reg = in.reg[sc];

    float c0 = cls[local];
    float c1 = cls[HW + local];
    float m  = fmaxf(c0, c1);
    float e0 = expf(c0 - m);
    float e1 = expf(c1 - m);
    float prob = e1 / (e0 + e1);

    float l0 = reg[local];
    float l1 = reg[HW + local];
    float l2 = reg[2 * HW + local];
    float l3 = reg[3 * HW + local];

    float sF  = (float)stride;
    float pcx = 0.5f * sF + (float)x * sF;
    float pcy = 0.5f * sF + (float)y * sF;
    float pwh = sF * 4.0f;

    float cx = pcx + ((l0 * 0.1f) * pwh);
    float cy = pcy + ((l1 * 0.1f) * pwh);
    float w  = pwh * expf(l2 * 0.2f);
    float h  = pwh * expf(l3 * 0.2f);
    float x1 = cx - w * 0.5f;
    float y1 = cy - h * 0.5f;
    float x2 = x1 + w;
    float y2 = y1 + h;

    dx1[gid] = x1; dy1[gid] = y1; dx2[gid] = x2; dy2[gid] = y2; dsc[gid] = prob;

    out[gid * 5 + 0] = 0.0f;
    out[gid * 5 + 1] = 0.0f;
    out[gid * 5 + 2] = 0.0f;
    out[gid * 5 + 3] = 0.0f;
    out[gid * 5 + 4] = 0.0f;

    if (prob > FINAL_TH) {
      unsigned int pos = atomicAdd(Mc, 1u);
      ckey[pos] = ((unsigned long long)__float_as_uint(prob) << 32) |
                  (unsigned int)(~(unsigned int)gid);
    }
  }
  grid.sync();

  // ---- phase 2: rank (4 subgroups of 256 per block; uniform trip counts) ----
  {
    unsigned long long* tile = smem8 + (size_t)(tid >> 8) * 256;  // 4 x 2KB
    const unsigned int M = *Mc;
    const int sg = tid >> 8, st = tid & 255;
    const int unit = bid * 4 + sg;            // 0..1023, need < 86*8=688
    const int bx = unit >> 3;                 // 0..127
    const int y  = unit & 7;
    const bool live = (bx < 86);
    const int p = bx * 256 + st;
    unsigned long long mykey = (live && p < (int)M) ? ckey[p] : 0ull;
    const int S  = (int)((M + NSLICE - 1) / NSLICE);
    const int lo = y * S;
    const int hi = min((int)M, lo + S);
    const int ntu = (S + 255) >> 8;           // UNIFORM across all units
    int partial = 0;
    for (int ti = 0; ti < ntu; ++ti) {
      int j = lo + ti * 256 + st;
      tile[st] = (live && j < hi) ? ckey[j] : 0ull;
      __syncthreads();
      if (live) {
#pragma unroll 8
        for (int q = 0; q < 256; ++q) partial += (tile[q] > mykey) ? 1 : 0;
      }
      __syncthreads();
    }
    if (live && p < (int)M) {
      unsigned int pack = (unsigned int)partial | (1u << 24);
      unsigned int old  = atomicAdd(&rank32[p], pack);
      unsigned int newv = old + pack;
      if ((newv >> 24) == NSLICE) {           // last slice to land scatters
        int r = (int)(newv & 0xFFFFFF);
        unsigned int orig = ~(unsigned int)(mykey & 0xffffffffull);
        sx1[r] = dx1[orig];
        sy1[r] = dy1[orig];
        sx2[r] = dx2[orig];
        sy2[r] = dy2[orig];
        sorig[r] = orig;
      }
    }
  }
  grid.sync();

  // ---- phase 3: pairs (unit-stride over the 22 x 342 tile grid) ----
  {
    float* cx1 = (float*)smem8;
    float* cy1 = cx1 + 1024;
    float* cx2 = cy1 + 1024;
    float* cy2 = cx2 + 1024;
    float* car = cy2 + 1024;
    unsigned* wvcnt  = (unsigned*)(car + 1024);
    unsigned* wvbase = wvcnt + 16;
    const int M = (int)*Mc;
    const int W = (M + 63) >> 6;
    const int g64 = tid >> 6, l = tid & 63;
    for (int u = bid; u < 22 * W_MAX; u += FUSED_B) {
      const int rw  = u / 22;
      const int cwg = (u % 22) << 4;
      if (rw >= W || cwg >= W || cwg + 22 < rw) continue;   // block-uniform
      const int cw = cwg + g64;
      {
        int c = (cw << 6) + l;
        if (cw < W && c < M) {
          float a = sx1[c], b = sy1[c], d = sx2[c], e = sy2[c];
          cx1[tid] = a; cy1[tid] = b; cx2[tid] = d; cy2[tid] = e;
          car[tid] = (d - a + 1.0f) * (e - b + 1.0f);
        }
      }
      __syncthreads();

      const int rwg = rw >> 2, cg2 = cw >> 2;
      const bool inW    = (cw < W);
      const bool isDiag = inW && (cw == rw);
      const bool isBand = inW && (cw < rw) && (cg2 >= rwg - 1);
      const bool isCsr  = inW && (cg2 >= rwg + 2);
      const bool any    = isDiag || isBand || isCsr;

      const int r = (rw << 6) + l;
      unsigned long long bits = 0ull;
      if (any && r < M) {
        float ax1 = sx1[r], ay1 = sy1[r], ax2 = sx2[r], ay2 = sy2[r];
        float aarea = (ax2 - ax1 + 1.0f) * (ay2 - ay1 + 1.0f);
        const int cmax = min(64, M - (cw << 6));
        const int sb = g64 << 6;
        for (int cc = 0; cc < cmax; ++cc) {
          float xx1 = fmaxf(ax1, cx1[sb + cc]);
          float yy1 = fmaxf(ay1, cy1[sb + cc]);
          float xx2 = fminf(ax2, cx2[sb + cc]);
          float yy2 = fminf(ay2, cy2[sb + cc]);
          float ww = fmaxf(xx2 - xx1 + 1.0f, 0.0f);
          float hh = fmaxf(yy2 - yy1 + 1.0f, 0.0f);
          float inter = ww * hh;
          float iou = inter / (aarea + car[sb + cc] - inter);
          if (iou > NMS_TH) bits |= (1ull << cc);
        }
      }
      if (isDiag)      diag[r] = bits;
      else if (isBand) bandT[(size_t)(rw - cw - 1) * NA + r] = bits;

      unsigned long long ball = 0ull;
      unsigned myrank = 0u;
      {
        bool mine = isCsr && (bits != 0ull);
        ball = __ballot(mine);
        myrank = (unsigned)__popcll(ball & ((1ull << l) - 1ull));
        if (l == 0) wvcnt[g64] = (unsigned)__popcll(ball);
      }
      __syncthreads();
      if (tid == 0) {
        unsigned tot = 0u;
        unsigned pre[16];
#pragma unroll
        for (int i = 0; i < 16; ++i) { pre[i] = tot; tot += wvcnt[i]; }
        unsigned base = (tot != 0u) ? atomicAdd(&wcnt[rw], tot) : 0u;
#pragma unroll
        for (int i = 0; i < 16; ++i) wvbase[i] = base + pre[i];
      }
      __syncthreads();
      if (isCsr && bits != 0ull) {
        unsigned slot = wbase_u((unsigned)rw) + wvbase[g64] + myrank;
        rlMeta[slot] = (unsigned short)(((unsigned)l << 9) | (unsigned)cw);
        rlBits[slot] = bits;
      }
    }
  }
  grid.sync();

  // ---- phase 4: scan — block 0 only (VERBATIM R6 protocol, 12 role waves) --
  if (bid != 0) return;
  {
    unsigned long long* sup  = smem8;                    // 342 u64
    unsigned long long* kmls = sup + W_MAX;              // 342 u64
    unsigned* lds_wcnt = (unsigned*)(kmls + W_MAX);      // 342 u32
    unsigned* gdone    = lds_wcnt + W_MAX;               // 86 u32
    unsigned* sflag_p  = gdone + GMAX;                   // 1 u32
    const int t = tid;
    const int g = t >> 6, l = t & 63;
    const int M = (int)*Mc;
    const int W = (M + 63) >> 6;
    const int NS = (W + 3) >> 2;

    for (int i = t; i < W_MAX; i += FUSED_T) {
      sup[i] = 0ull; kmls[i] = 0ull; lds_wcnt[i] = wcnt[i];
    }
    for (int i = t; i < GMAX; i += FUSED_T) gdone[i] = 0u;
    if (t == 0) *sflag_p = 0u;
    block_bar();

    if (g == 0) {
      // -------- scanner wave --------
      __builtin_amdgcn_s_setprio(1);
      const unsigned long long lowm = (1ull << l) - 1ull;
      unsigned long long dc[4], dn[4];
      unsigned long long bc[4][NBAND], bn[4][NBAND];
      unsigned long long kp[4] = {0ull, 0ull, 0ull, 0ull};
#pragma unroll
      for (int i = 0; i < 4; ++i) {
        int v = i, vc = (v < W) ? v : 0;
        dc[i] = diag[(vc << 6) + l];
#pragma unroll
        for (int d = 1; d <= NBAND; ++d)
          if (d <= i + 4) bc[i][d - 1] = bandT[(size_t)(d - 1) * NA + (vc << 6) + l];
      }
#pragma unroll
      for (int i = 0; i < 4; ++i) {
        int v = 4 + i, vc = (v < W) ? v : 0;
        dn[i] = diag[(vc << 6) + l];
#pragma unroll
        for (int d = 1; d <= NBAND; ++d)
          if (d <= i + 4) bn[i][d - 1] = bandT[(size_t)(d - 1) * NA + (vc << 6) + l];
      }
      for (int s = 0; s < NS; ++s) {
        const int v0 = s << 2;
        unsigned long long accp[4];
#pragma unroll
        for (int i = 0; i < 4; ++i) {
          unsigned long long a = 0ull;
#pragma unroll
          for (int d = 1; d <= NBAND; ++d)
            if (d <= i + 4 && d > i) a |= (bc[i][d - 1] & kp[i - d + 4]);
          accp[i] = a;
        }
        if (s >= 2) {
          while (*(volatile unsigned*)&gdone[s - 2] < (unsigned)NPUSH) {}
          asm volatile("" ::: "memory");
        }
        unsigned long long sv[4];
#pragma unroll
        for (int i = 0; i < 4; ++i)
          sv[i] = (v0 + i < W) ? sup[v0 + i] : 0ull;
        unsigned long long kc[4];
#pragma unroll
        for (int i = 0; i < 4; ++i) {
          const int v = v0 + i;
          unsigned long long kept = 0ull;
          if (v < W) {
            unsigned long long acc = accp[i];
#pragma unroll
            for (int d = 1; d <= 3; ++d)
              if (d <= i) acc |= (bc[i][d - 1] & kc[i - d]);
            unsigned long long incoming = __ballot(acc != 0ull);
            const int n = min(64, M - (v << 6));
            unsigned long long wm = (n >= 64) ? ~0ull : ((1ull << n) - 1ull);
            unsigned long long pend = (~(sv[i] | incoming)) & wm;
            const unsigned long long dv = dc[i] & lowm;
            unsigned long long dead = ~pend, und = pend;
            while (und) {
              unsigned long long bS = __ballot((dv & kept) != 0ull) & und;
              unsigned long long bK = __ballot((dv & ~dead) == 0ull) & und;
              kept |= bK; dead |= bS; und &= ~(bK | bS);
            }
            if (l == i) kmls[v] = kept;
          }
          kc[i] = kept;
        }
        asm volatile("s_waitcnt lgkmcnt(0)" ::: "memory");
        if (l == 0) *(volatile unsigned*)sflag_p = (unsigned)(s + 1);
#pragma unroll
        for (int i = 0; i < 4; ++i) kp[i] = kc[i];
#pragma unroll
        for (int i = 0; i < 4; ++i) {
          dc[i] = dn[i];
#pragma unroll
          for (int d = 0; d < NBAND; ++d)
            if (d <= i + 3) bc[i][d] = bn[i][d];
        }
        const int vn = v0 + 8;
#pragma unroll
        for (int i = 0; i < 4; ++i) {
          int v = vn + i, vc = (v < W) ? v : 0;
          dn[i] = diag[(vc << 6) + l];
#pragma unroll
          for (int d = 1; d <= NBAND; ++d)
            if (d <= i + 4) bn[i][d - 1] = bandT[(size_t)(d - 1) * NA + (vc << 6) + l];
        }
      }
      __builtin_amdgcn_s_setprio(0);
    } else if (g <= NPUSH) {
      // -------- pusher lanes: dense ranges, static-address depth-2 --------
      const int p = (g - 1) * 64 + l;            // 0..703

#define PUSH_LOAD(mX, bX, gs)                                               \
      {                                                                     \
        _Pragma("unroll")                                                   \
        for (int i = 0; i < 4; ++i) {                                       \
          int v = (gs) * 4 + i;                                             \
          unsigned vc = (v < W) ? (unsigned)v : 0u;                         \
          unsigned base = wbase_u(vc);                                      \
          unsigned i0 = base + (unsigned)p;   if (i0 >= TOT_ENT) i0 = 0u;   \
          unsigned i1 = i0 + (unsigned)PLANES; if (i1 >= TOT_ENT) i1 = 0u;  \
          mX[i][0] = (unsigned)rlMeta[i0]; bX[i][0] = rlBits[i0];           \
          mX[i][1] = (unsigned)rlMeta[i1]; bX[i][1] = rlBits[i1];           \
        }                                                                   \
      }

      unsigned mA[4][2], mB[4][2];
      unsigned long long bA[4][2], bB[4][2];
      PUSH_LOAD(mA, bA, 0)
      PUSH_LOAD(mB, bB, 1)
      for (int s = 0; s < NS; ++s) {
        while (*(volatile unsigned*)sflag_p < (unsigned)(s + 1))
          __builtin_amdgcn_s_sleep(1);
        asm volatile("" ::: "memory");
#pragma unroll
        for (int i = 0; i < 4; ++i) {
          const int v = (s << 2) + i;
          if (v < W) {
            const unsigned tw = lds_wcnt[v];
            const unsigned long long km = kmls[v];
            if (km != 0ull && tw != 0u) {
              if ((unsigned)p < tw && ((km >> (mA[i][0] >> 9)) & 1ull))
                atomicOr(&sup[mA[i][0] & 511u], bA[i][0]);
              if ((unsigned)p + (unsigned)PLANES < tw &&
                  ((km >> (mA[i][1] >> 9)) & 1ull))
                atomicOr(&sup[mA[i][1] & 511u], bA[i][1]);
              if (tw > 2u * (unsigned)PLANES) {
                unsigned base = wbase_u((unsigned)v);
                for (unsigned ii = (unsigned)p + 2u * (unsigned)PLANES;
                     ii < tw; ii += (unsigned)PLANES) {
                  unsigned sl = base + ii; if (sl >= TOT_ENT) sl = TOT_ENT - 1u;
                  unsigned mm = (unsigned)rlMeta[sl];
                  if ((km >> (mm >> 9)) & 1ull)
                    atomicOr(&sup[mm & 511u], rlBits[sl]);
                }
              }
            }
          }
        }
        asm volatile("s_waitcnt lgkmcnt(0)" ::: "memory");
        if (l == 0) atomicAdd(&gdone[s], 1u);
#pragma unroll
        for (int i = 0; i < 4; ++i) {
          mA[i][0] = mB[i][0]; mA[i][1] = mB[i][1];
          bA[i][0] = bB[i][0]; bA[i][1] = bB[i][1];
        }
        PUSH_LOAD(mB, bB, s + 2)
      }
#undef PUSH_LOAD
    }
    // waves 12-15: no role; fall through to the final barrier
    block_bar();

    for (int i = t; i < (W << 6); i += FUSED_T) {
      if ((kmls[i >> 6] >> (i & 63)) & 1ull) {
        unsigned int orig = sorig[i];
        out[(size_t)orig * 5 + 0] = dx1[orig];
        out[(size_t)orig * 5 + 1] = dy1[orig];
        out[(size_t)orig * 5 + 2] = dx2[orig];
        out[(size_t)orig * 5 + 3] = dy2[orig];
        out[(size_t)orig * 5 + 4] = dsc[orig];
      }
    }
  }
}

// ================= original split kernels (fallbacks) ========================
__global__ void decode_kernel(Inputs in,
                              float* __restrict__ dx1, float* __restrict__ dy1,
                              float* __restrict__ dx2, float* __restrict__ dy2,
                              float* __restrict__ dsc,
                              unsigned long long* __restrict__ ckey,
                              unsigned int* __restrict__ Mc,
                              unsigned int* __restrict__ rank32,
                              unsigned int* __restrict__ wcnt,
                              float* __restrict__ out) {
#pragma clang fp contract(off)
  int gid = blockIdx.x * blockDim.x + threadIdx.x;
  if (gid >= N_TOTAL) return;

  rank32[gid] = 0u;
  wcnt[gid] = 0u;
  if (gid < NA - N_TOTAL) wcnt[N_TOTAL + gid] = 0u;

  int sc, local;
  if      (gid < 16384) { sc = 0; local = gid;         }
  else if (gid < 20480) { sc = 1; local = gid - 16384; }
  else if (gid < 21504) { sc = 2; local = gid - 20480; }
  else if (gid < 21760) { sc = 3; local = gid - 21504; }
  else if (gid < 21824) { sc = 4; local = gid - 21760; }
  else                  { sc = 5; local = gid - 21824; }

  const int Wd     = 128 >> sc;
  const int stride = 4 << sc;
  const int HW     = Wd * Wd;
  const int x = local & (Wd - 1);
  const int y = local >> (7 - sc);

  const float* cls = in.cls[sc];
  const float* reg = in.reg[sc];

  float c0 = cls[local];
  float c1 = cls[HW + local];
  float m  = fmaxf(c0, c1);
  float e0 = expf(c0 - m);
  float e1 = expf(c1 - m);
  float prob = e1 / (e0 + e1);

  float l0 = reg[local];
  float l1 = reg[HW + local];
  float l2 = reg[2 * HW + local];
  float l3 = reg[3 * HW + local];

  float sF  = (float)stride;
  float pcx = 0.5f * sF + (float)x * sF;
  float pcy = 0.5f * sF + (float)y * sF;
  float pwh = sF * 4.0f;

  float cx = pcx + ((l0 * 0.1f) * pwh);
  float cy = pcy + ((l1 * 0.1f) * pwh);
  float w  = pwh * expf(l2 * 0.2f);
  float h  = pwh * expf(l3 * 0.2f);
  float x1 = cx - w * 0.5f;
  float y1 = cy - h * 0.5f;
  float x2 = x1 + w;
  float y2 = y1 + h;

  dx1[gid] = x1; dy1[gid] = y1; dx2[gid] = x2; dy2[gid] = y2; dsc[gid] = prob;

  out[gid * 5 + 0] = 0.0f;
  out[gid * 5 + 1] = 0.0f;
  out[gid * 5 + 2] = 0.0f;
  out[gid * 5 + 3] = 0.0f;
  out[gid * 5 + 4] = 0.0f;

  if (prob > FINAL_TH) {
    unsigned int pos = atomicAdd(Mc, 1u);
    ckey[pos] = ((unsigned long long)__float_as_uint(prob) << 32) |
                (unsigned int)(~(unsigned int)gid);
  }
}

__global__ void __launch_bounds__(256)
rank_kernel(const unsigned long long* __restrict__ ckey,
            const unsigned int* __restrict__ Mc,
            const float* __restrict__ dx1, const float* __restrict__ dy1,
            const float* __restrict__ dx2, const float* __restrict__ dy2,
            float* __restrict__ sx1, float* __restrict__ sy1,
            float* __restrict__ sx2, float* __restrict__ sy2,
            unsigned int* __restrict__ sorig,
            unsigned int* __restrict__ rank32) {
  __shared__ unsigned long long tile[256];
  const unsigned int M = *Mc;
  if (blockIdx.x * 256u >= M) return;
  const int t = (int)threadIdx.x;
  const int p = (int)blockIdx.x * 256 + t;
  unsigned long long mykey = (p < (int)M) ? ckey[p] : 0ull;
  const int S  = (int)((M + NSLICE - 1) / NSLICE);
  const int lo = (int)blockIdx.y * S;
  const int hi = min((int)M, lo + S);
  int partial = 0;
  const int nt = (hi > lo) ? ((hi - lo + 255) >> 8) : 0;
  for (int ti = 0; ti < nt; ++ti) {
    int j = lo + ti * 256 + t;
    tile[t] = (j < hi) ? ckey[j] : 0ull;
    __syncthreads();
#pragma unroll 8
    for (int q = 0; q < 256; ++q) partial += (tile[q] > mykey) ? 1 : 0;
    __syncthreads();
  }
  if (p < (int)M) {
    unsigned int pack = (unsigned int)partial | (1u << 24);
    unsigned int old  = atomicAdd(&rank32[p], pack);
    unsigned int newv = old + pack;
    if ((newv >> 24) == NSLICE) {
      int r = (int)(newv & 0xFFFFFF);
      unsigned int orig = ~(unsigned int)(mykey & 0xffffffffull);
      sx1[r] = dx1[orig];
      sy1[r] = dy1[orig];
      sx2[r] = dx2[orig];
      sy2[r] = dy2[orig];
      sorig[r] = orig;
    }
  }
}

__global__ void __launch_bounds__(1024)
pairs_kernel(const float* __restrict__ sx1, const float* __restrict__ sy1,
             const float* __restrict__ sx2, const float* __restrict__ sy2,
             const unsigned int* __restrict__ Mc,
             unsigned long long* __restrict__ diag,
             unsigned long long* __restrict__ bandT,
             unsigned int* __restrict__ wcnt,
             unsigned short* __restrict__ rlMeta,
             unsigned long long* __restrict__ rlBits) {
#pragma clang fp contract(off)
  const int M = (int)*Mc;
  const int W = (M + 63) >> 6;
  const int rw = (int)blockIdx.y;
  const int cwg = (int)blockIdx.x << 4;
  if (rw >= W || cwg >= W || cwg + 22 < rw) return;

  const int t = (int)threadIdx.x;
  const int g = t >> 6, l = t & 63;
  const int cw = cwg + g;

  __shared__ float cx1[1024], cy1[1024], cx2[1024], cy2[1024], car[1024];
  __shared__ unsigned wvcnt[16], wvbase[16];
  {
    int c = (cw << 6) + l;
    if (cw < W && c < M) {
      float a = sx1[c], b = sy1[c], d = sx2[c], e = sy2[c];
      cx1[t] = a; cy1[t] = b; cx2[t] = d; cy2[t] = e;
      car[t] = (d - a + 1.0f) * (e - b + 1.0f);
    }
  }
  __syncthreads();

  const int rwg = rw >> 2, cg = cw >> 2;
  const bool inW    = (cw < W);
  const bool isDiag = inW && (cw == rw);
  const bool isBand = inW && (cw < rw) && (cg >= rwg - 1);
  const bool isCsr  = inW && (cg >= rwg + 2);
  const bool any    = isDiag || isBand || isCsr;

  const int r = (rw << 6) + l;
  unsigned long long bits = 0ull;
  if (any && r < M) {
    float ax1 = sx1[r], ay1 = sy1[r], ax2 = sx2[r], ay2 = sy2[r];
    float aarea = (ax2 - ax1 + 1.0f) * (ay2 - ay1 + 1.0f);
    const int cmax = min(64, M - (cw << 6));
    const int sb = g << 6;
    for (int cc = 0; cc < cmax; ++cc) {
      float xx1 = fmaxf(ax1, cx1[sb + cc]);
      float yy1 = fmaxf(ay1, cy1[sb + cc]);
      float xx2 = fminf(ax2, cx2[sb + cc]);
      float yy2 = fminf(ay2, cy2[sb + cc]);
      float ww = fmaxf(xx2 - xx1 + 1.0f, 0.0f);
      float hh = fmaxf(yy2 - yy1 + 1.0f, 0.0f);
      float inter = ww * hh;
      float iou = inter / (aarea + car[sb + cc] - inter);
      if (iou > NMS_TH) bits |= (1ull << cc);
    }
  }
  if (isDiag)      diag[r] = bits;
  else if (isBand) bandT[(size_t)(rw - cw - 1) * NA + r] = bits;

  unsigned long long ball = 0ull;
  unsigned myrank = 0u;
  {
    bool mine = isCsr && (bits != 0ull);
    ball = __ballot(mine);
    myrank = (unsigned)__popcll(ball & ((1ull << l) - 1ull));
    if (l == 0) wvcnt[g] = (unsigned)__popcll(ball);
  }
  __syncthreads();
  if (t == 0) {
    unsigned tot = 0u;
    unsigned pre[16];
#pragma unroll
    for (int i = 0; i < 16; ++i) { pre[i] = tot; tot += wvcnt[i]; }
    unsigned base = (tot != 0u) ? atomicAdd(&wcnt[rw], tot) : 0u;
#pragma unroll
    for (int i = 0; i < 16; ++i) wvbase[i] = base + pre[i];
  }
  __syncthreads();
  if (isCsr && bits != 0ull) {
    unsigned slot = wbase_u((unsigned)rw) + wvbase[g] + myrank;
    rlMeta[slot] = (unsigned short)(((unsigned)l << 9) | (unsigned)cw);
    rlBits[slot] = bits;
  }
}

__global__ void __launch_bounds__(SCAN_T, 3)
scan_kernel(const unsigned long long* __restrict__ diag,
            const unsigned long long* __restrict__ bandT,
            const unsigned int* __restrict__ wcnt,
            const unsigned short* __restrict__ rlMeta,
            const unsigned long long* __restrict__ rlBits,
            const unsigned int* __restrict__ sorig,
            const unsigned int* __restrict__ Mc,
            const float* __restrict__ dx1, const float* __restrict__ dy1,
            const float* __restrict__ dx2, const float* __restrict__ dy2,
            const float* __restrict__ dsc,
            float* __restrict__ out) {
  __shared__ unsigned long long sup[W_MAX];
  __shared__ unsigned long long kmls[W_MAX];
  __shared__ unsigned lds_wcnt[W_MAX];
  __shared__ unsigned gdone[GMAX];
  __shared__ volatile unsigned sflag;
  const int t = (int)threadIdx.x;
  const int g = t >> 6, l = t & 63;
  const int M = (int)*Mc;
  const int W = (M + 63) >> 6;
  const int NS = (W + 3) >> 2;

  for (int i = t; i < W_MAX; i += SCAN_T) {
    sup[i] = 0ull; kmls[i] = 0ull; lds_wcnt[i] = wcnt[i];
  }
  for (int i = t; i < GMAX; i += SCAN_T) gdone[i] = 0u;
  if (t == 0) sflag = 0u;
  block_bar();

  if (g == 0) {
    __builtin_amdgcn_s_setprio(1);
    const unsigned long long lowm = (1ull << l) - 1ull;
    unsigned long long dc[4], dn[4];
    unsigned long long bc[4][NBAND], bn[4][NBAND];
    unsigned long long kp[4] = {0ull, 0ull, 0ull, 0ull};
#pragma unroll
    for (int i = 0; i < 4; ++i) {
      int v = i, vc = (v < W) ? v : 0;
      dc[i] = diag[(vc << 6) + l];
#pragma unroll
      for (int d = 1; d <= NBAND; ++d)
        if (d <= i + 4) bc[i][d - 1] = bandT[(size_t)(d - 1) * NA + (vc << 6) + l];
    }
#pragma unroll
    for (int i = 0; i < 4; ++i) {
      int v = 4 + i, vc = (v < W) ? v : 0;
      dn[i] = diag[(vc << 6) + l];
#pragma unroll
      for (int d = 1; d <= NBAND; ++d)
        if (d <= i + 4) bn[i][d - 1] = bandT[(size_t)(d - 1) * NA + (vc << 6) + l];
    }
    for (int s = 0; s < NS; ++s) {
      const int v0 = s << 2;
      unsigned long long accp[4];
#pragma unroll
      for (int i = 0; i < 4; ++i) {
        unsigned long long a = 0ull;
#pragma unroll
        for (int d = 1; d <= NBAND; ++d)
          if (d <= i + 4 && d > i) a |= (bc[i][d - 1] & kp[i - d + 4]);
        accp[i] = a;
      }
      if (s >= 2) {
        while (*(volatile unsigned*)&gdone[s - 2] < (unsigned)NPUSH) {}
        asm volatile("" ::: "memory");
      }
      unsigned long long sv[4];
#pragma unroll
      for (int i = 0; i < 4; ++i)
        sv[i] = (v0 + i < W) ? sup[v0 + i] : 0ull;
      unsigned long long kc[4];
#pragma unroll
      for (int i = 0; i < 4; ++i) {
        const int v = v0 + i;
        unsigned long long kept = 0ull;
        if (v < W) {
          unsigned long long acc = accp[i];
#pragma unroll
          for (int d = 1; d <= 3; ++d)
            if (d <= i) acc |= (bc[i][d - 1] & kc[i - d]);
          unsigned long long incoming = __ballot(acc != 0ull);
          const int n = min(64, M - (v << 6));
          unsigned long long wm = (n >= 64) ? ~0ull : ((1ull << n) - 1ull);
          unsigned long long pend = (~(sv[i] | incoming)) & wm;
          const unsigned long long dv = dc[i] & lowm;
          unsigned long long dead = ~pend, und = pend;
          while (und) {
            unsigned long long bS = __ballot((dv & kept) != 0ull) & und;
            unsigned long long bK = __ballot((dv & ~dead) == 0ull) & und;
            kept |= bK; dead |= bS; und &= ~(bK | bS);
          }
          if (l == i) kmls[v] = kept;
        }
        kc[i] = kept;
      }
      asm volatile("s_waitcnt lgkmcnt(0)" ::: "memory");
      if (l == 0) sflag = (unsigned)(s + 1);
#pragma unroll
      for (int i = 0; i < 4; ++i) kp[i] = kc[i];
#pragma unroll
      for (int i = 0; i < 4; ++i) {
        dc[i] = dn[i];
#pragma unroll
        for (int d = 0; d < NBAND; ++d)
          if (d <= i + 3) bc[i][d] = bn[i][d];
      }
      const int vn = v0 + 8;
#pragma unroll
      for (int i = 0; i < 4; ++i) {
        int v = vn + i, vc = (v < W) ? v : 0;
        dn[i] = diag[(vc << 6) + l];
#pragma unroll
        for (int d = 1; d <= NBAND; ++d)
          if (d <= i + 4) bn[i][d - 1] = bandT[(size_t)(d - 1) * NA + (vc << 6) + l];
      }
    }
    __builtin_amdgcn_s_setprio(0);
  } else {
    const int p = (g - 1) * 64 + l;

#define PUSH_LOAD(mX, bX, gs)                                               \
    {                                                                       \
      _Pragma("unroll")                                                     \
      for (int i = 0; i < 4; ++i) {                                         \
        int v = (gs) * 4 + i;                                               \
        unsigned vc = (v < W) ? (unsigned)v : 0u;                           \
        unsigned base = wbase_u(vc);                                        \
        unsigned i0 = base + (unsigned)p;   if (i0 >= TOT_ENT) i0 = 0u;     \
        unsigned i1 = i0 + (unsigned)PLANES; if (i1 >= TOT_ENT) i1 = 0u;    \
        mX[i][0] = (unsigned)rlMeta[i0]; bX[i][0] = rlBits[i0];             \
        mX[i][1] = (unsigned)rlMeta[i1]; bX[i][1] = rlBits[i1];             \
      }                                                                     \
    }

    unsigned mA[4][2], mB[4][2];
    unsigned long long bA[4][2], bB[4][2];
    PUSH_LOAD(mA, bA, 0)
    PUSH_LOAD(mB, bB, 1)
    for (int s = 0; s < NS; ++s) {
      while (sflag < (unsigned)(s + 1)) __builtin_amdgcn_s_sleep(1);
      asm volatile("" ::: "memory");
#pragma unroll
      for (int i = 0; i < 4; ++i) {
        const int v = (s << 2) + i;
        if (v < W) {
          const unsigned tw = lds_wcnt[v];
          const unsigned long long km = kmls[v];
          if (km != 0ull && tw != 0u) {
            if ((unsigned)p < tw && ((km >> (mA[i][0] >> 9)) & 1ull))
              atomicOr(&sup[mA[i][0] & 511u], bA[i][0]);
            if ((unsigned)p + (unsigned)PLANES < tw &&
                ((km >> (mA[i][1] >> 9)) & 1ull))
              atomicOr(&sup[mA[i][1] & 511u], bA[i][1]);
            if (tw > 2u * (unsigned)PLANES) {
              unsigned base = wbase_u((unsigned)v);
              for (unsigned ii = (unsigned)p + 2u * (unsigned)PLANES;
                   ii < tw; ii += (unsigned)PLANES) {
                unsigned sl = base + ii; if (sl >= TOT_ENT) sl = TOT_ENT - 1u;
                unsigned mm = (unsigned)rlMeta[sl];
                if ((km >> (mm >> 9)) & 1ull)
                  atomicOr(&sup[mm & 511u], rlBits[sl]);
              }
            }
          }
        }
      }
      asm volatile("s_waitcnt lgkmcnt(0)" ::: "memory");
      if (l == 0) atomicAdd(&gdone[s], 1u);
#pragma unroll
      for (int i = 0; i < 4; ++i) {
        mA[i][0] = mB[i][0]; mA[i][1] = mB[i][1];
        bA[i][0] = bB[i][0]; bA[i][1] = bB[i][1];
      }
      PUSH_LOAD(mB, bB, s + 2)
    }
#undef PUSH_LOAD
  }
  block_bar();

  for (int i = t; i < (W << 6); i += SCAN_T) {
    if ((kmls[i >> 6] >> (i & 63)) & 1ull) {
      unsigned int orig = sorig[i];
      out[(size_t)orig * 5 + 0] = dx1[orig];
      out[(size_t)orig * 5 + 1] = dy1[orig];
      out[(size_t)orig * 5 + 2] = dx2[orig];
      out[(size_t)orig * 5 + 3] = dy2[orig];
      out[(size_t)orig * 5 + 4] = dsc[orig];
    }
  }
}

// ------------------------------------------------- fallback NMS (tiny ws) ---
__global__ void __launch_bounds__(1024)
nms_kernel(const float* __restrict__ sx1, const float* __restrict__ sy1,
           const float* __restrict__ sx2, const float* __restrict__ sy2,
           const unsigned int* __restrict__ sorig,
           const unsigned int* __restrict__ Mc,
           unsigned int* __restrict__ keepflag) {
#pragma clang fp contract(off)
  __shared__ unsigned long long sup[W_MAX];
  __shared__ unsigned long long inrow[64];
  __shared__ float wx1[64], wy1[64], wx2[64], wy2[64], warea[64];
  __shared__ unsigned long long keptmask_sh;

  const int t = (int)threadIdx.x;
  const int M = (int)*Mc;
  const int W = (M + 63) >> 6;

  for (int i = t; i < W_MAX; i += 1024) sup[i] = 0ull;
  __syncthreads();

  for (int w = 0; w < W; ++w) {
    const int base = w << 6;
    const int n = min(64, M - base);
    if (t < 64) {
      if (t < n) {
        float a = sx1[base + t], b = sy1[base + t];
        float c = sx2[base + t], d = sy2[base + t];
        wx1[t] = a; wy1[t] = b; wx2[t] = c; wy2[t] = d;
        warea[t] = (c - a + 1.0f) * (d - b + 1.0f);
      }
    } else if (t < 128) {
      inrow[t - 64] = 0ull;
    }
    __syncthreads();
    {
      int r = t & 63, seg = t >> 6;
      unsigned long long bits = 0ull;
      if (r < n) {
        float ax1 = wx1[r], ay1 = wy1[r], ax2 = wx2[r], ay2 = wy2[r];
        float aarea = warea[r];
        for (int c = seg * 4; c < seg * 4 + 4; ++c) {
          if (c > r && c < n) {
            float xx1 = fmaxf(ax1, wx1[c]);
            float yy1 = fmaxf(ay1, wy1[c]);
            float xx2 = fminf(ax2, wx2[c]);
            float yy2 = fminf(ay2, wy2[c]);
            float ww = fmaxf(xx2 - xx1 + 1.0f, 0.0f);
            float hh = fmaxf(yy2 - yy1 + 1.0f, 0.0f);
            float inter = ww * hh;
            float iou = inter / (aarea + warea[c] - inter);
            if (iou > NMS_TH) bits |= (1ull << c);
          }
        }
      }
      if (bits) atomicOr(&inrow[r], bits);
    }
    __syncthreads();
    if (t < 64) {
      unsigned long long wordmask = (n >= 64) ? ~0ull : ((1ull << n) - 1ull);
      unsigned long long pending = (~sup[w]) & wordmask;
      unsigned long long kept = 0ull;
      while (pending) {
        int i = __builtin_ctzll(pending);
        kept |= (1ull << i);
        pending &= ~(inrow[i] | (1ull << i));
      }
      if (t == 0) keptmask_sh = kept;
      if (t < n && ((kept >> t) & 1ull)) keepflag[sorig[base + t]] = 1u;
    }
    __syncthreads();
    unsigned long long km = keptmask_sh;
    if (km) {
      int wid = t >> 6, lane = t & 63;
      for (int jw = w + 1 + wid; (jw << 6) < M; jw += 16) {
        int j = (jw << 6) + lane;
        bool supj = false;
        if (j < M) {
          float jx1 = sx1[j], jy1 = sy1[j], jx2 = sx2[j], jy2 = sy2[j];
          float jarea = (jx2 - jx1 + 1.0f) * (jy2 - jy1 + 1.0f);
          unsigned long long mm = km;
          while (mm) {
            int r = __builtin_ctzll(mm);
            mm &= mm - 1ull;
            float xx1 = fmaxf(wx1[r], jx1);
            float yy1 = fmaxf(wy1[r], jy1);
            float xx2 = fminf(wx2[r], jx2);
            float yy2 = fminf(wy2[r], jy2);
            float ww = fmaxf(xx2 - xx1 + 1.0f, 0.0f);
            float hh = fmaxf(yy2 - yy1 + 1.0f, 0.0f);
            float inter = ww * hh;
            float iou = inter / (warea[r] + jarea - inter);
            if (iou > NMS_TH) { supj = true; break; }
          }
        }
        unsigned long long bal = __ballot(supj);
        if (lane == 0 && bal) atomicOr(&sup[jw], bal);
      }
    }
    __syncthreads();
  }
}

__global__ void output_kernel(const float* __restrict__ dx1, const float* __restrict__ dy1,
                              const float* __restrict__ dx2, const float* __restrict__ dy2,
                              const float* __restrict__ dsc,
                              const unsigned int* __restrict__ keepflag,
                              float* __restrict__ out) {
#pragma clang fp contract(off)
  int gid = blockIdx.x * blockDim.x + threadIdx.x;
  if (gid >= N_TOTAL) return;
  float f = keepflag[gid] ? 1.0f : 0.0f;
  out[gid * 5 + 0] = dx1[gid] * f;
  out[gid * 5 + 1] = dy1[gid] * f;
  out[gid * 5 + 2] = dx2[gid] * f;
  out[gid * 5 + 3] = dy2[gid] * f;
  out[gid * 5 + 4] = dsc[gid] * f;
}

// ---------------------------------------------------------------- launch ----
extern "C" void kernel_launch(void* const* d_in, const int* in_sizes, int n_in,
                              void* d_out, int out_size, void* d_ws, size_t ws_size,
                              hipStream_t stream) {
  (void)in_sizes; (void)n_in; (void)out_size;

  Inputs in;
  for (int i = 0; i < 6; ++i) {
    in.cls[i] = (const float*)d_in[2 * i];
    in.reg[i] = (const float*)d_in[2 * i + 1];
  }

  char* ws = (char*)d_ws;
  size_t o = 0;
  float* dx1 = (float*)(ws + o); o += (size_t)NA * 4;
  float* dy1 = (float*)(ws + o); o += (size_t)NA * 4;
  float* dx2 = (float*)(ws + o); o += (size_t)NA * 4;
  float* dy2 = (float*)(ws + o); o += (size_t)NA * 4;
  float* dsc = (float*)(ws + o); o += (size_t)NA * 4;
  unsigned long long* ckey = (unsigned long long*)(ws + o); o += (size_t)NA * 8;
  float* sx1 = (float*)(ws + o); o += (size_t)NA * 4;
  float* sy1 = (float*)(ws + o); o += (size_t)NA * 4;
  float* sx2 = (float*)(ws + o); o += (size_t)NA * 4;
  float* sy2 = (float*)(ws + o); o += (size_t)NA * 4;
  unsigned int* sorig = (unsigned int*)(ws + o); o += (size_t)NA * 4;
  unsigned int* keepflag = (unsigned int*)(ws + o); o += (size_t)NA * 4;
  unsigned int* rank32 = (unsigned int*)(ws + o); o += (size_t)NA * 4;
  unsigned int* wcnt = (unsigned int*)(ws + o); o += (size_t)NA * 4;
  unsigned int* Mc = (unsigned int*)(ws + o); o += 64;
  o = (o + 511) & ~(size_t)511;
  unsigned long long* diag = (unsigned long long*)(ws + o); o += (size_t)NA * 8;
  unsigned long long* bandT = (unsigned long long*)(ws + o); o += (size_t)NBAND * NA * 8;
  unsigned long long* rlBits = (unsigned long long*)(ws + o); o += (size_t)TOT_ENT * 8;
  unsigned short* rlMeta = (unsigned short*)(ws + o); o += (size_t)TOT_ENT * 2;
  size_t need = o;                            // ~41 MiB
  const bool fast = (need <= ws_size);        // ws_size constant -> graph-safe

  const int nb = (N_TOTAL + 255) / 256;  // 86

  if (fast) {
    float* outp = (float*)d_out;
    void* kargs[] = {
      (void*)&in,
      (void*)&dx1, (void*)&dy1, (void*)&dx2, (void*)&dy2, (void*)&dsc,
      (void*)&ckey,
      (void*)&sx1, (void*)&sy1, (void*)&sx2, (void*)&sy2,
      (void*)&sorig, (void*)&rank32, (void*)&wcnt, (void*)&Mc,
      (void*)&diag, (void*)&bandT, (void*)&rlMeta, (void*)&rlBits,
      (void*)&outp
    };
    hipError_t e = hipLaunchCooperativeKernel(
        (const void*)fused_kernel, dim3(FUSED_B), dim3(FUSED_T),
        kargs, 0, stream);
    if (e == hipSuccess) return;
    // cooperative launch unavailable -> verified 5-launch path (R6)
    (void)hipGetLastError();
    (void)hipMemsetAsync((void*)Mc, 0, 64, stream);
    decode_kernel<<<nb, 256, 0, stream>>>(in, dx1, dy1, dx2, dy2, dsc, ckey, Mc,
                                          rank32, wcnt, (float*)d_out);
    rank_kernel<<<dim3(nb, NSLICE), 256, 0, stream>>>(ckey, Mc, dx1, dy1, dx2, dy2,
                                                      sx1, sy1, sx2, sy2, sorig,
                                                      rank32);
    pairs_kernel<<<dim3(22, W_MAX), 1024, 0, stream>>>(sx1, sy1, sx2, sy2, Mc,
                                                       diag, bandT, wcnt, rlMeta, rlBits);
    scan_kernel<<<1, SCAN_T, 0, stream>>>(diag, bandT, wcnt, rlMeta, rlBits, sorig, Mc,
                                          dx1, dy1, dx2, dy2, dsc, (float*)d_out);
  } else {
    // fallback: zero keepflag + rank32 + wcnt + Mc (contiguous)
    (void)hipMemsetAsync((void*)keepflag, 0, (size_t)NA * 12 + 64, stream);
    decode_kernel<<<nb, 256, 0, stream>>>(in, dx1, dy1, dx2, dy2, dsc, ckey, Mc,
                                          rank32, wcnt, (float*)d_out);
    rank_kernel<<<dim3(nb, NSLICE), 256, 0, stream>>>(ckey, Mc, dx1, dy1, dx2, dy2,
                                                      sx1, sy1, sx2, sy2, sorig,
                                                      rank32);
    nms_kernel<<<1, 1024, 0, stream>>>(sx1, sy1, sx2, sy2, sorig, Mc, keepflag);
    output_kernel<<<nb, 256, 0, stream>>>(dx1, dy1, dx2, dy2, dsc, keepflag,
                                          (float*)d_out);
  }
}

// Round 14
// 270.553 us; speedup vs baseline: 1.6129x; 1.6129x over previous
//
#include <hip/hip_runtime.h>
#include <stdint.h>

#define N_TOTAL 21840
#define NA      21888          // N_TOTAL rounded up to multiple of 64
#define W_MAX   342            // ceil(21840/64)
#define TOT_ENT 3753792u       // 64 * (342*343/2)  triangular dense capacity
#define NMS_TH  0.3f
#define FINAL_TH 0.5f
#define NSLICE  8              // rank range-split factor
#define SCAN_T  768            // scan block: 1 scanner wave + 11 pusher waves
#define NPUSH   11             // pusher wave count (SCAN_T/64 - 1)
#define PLANES  704            // NPUSH*64 pusher lanes
#define GRP     4              // words per scan group
#define NBAND   7              // 2*GRP-1 transposed band arrays
#define GMAX    86             // max groups = ceil(W_MAX/GRP)
#define NROWS   26             // staged rows/group: 4 diag + 22 bands
#define NSTG    13             // global_load_lds instrs/group (2 rows each)

struct Inputs { const float* cls[6]; const float* reg[6]; };

// Raw barrier: drains LDS (lgkmcnt) but NOT vmem (vmcnt).
__device__ __forceinline__ void block_bar() {
  asm volatile("s_waitcnt lgkmcnt(0)\n\ts_barrier" ::: "memory");
}

// Dense per-word base: word w owns 64*(342-w) entry slots (triangular).
__device__ __forceinline__ unsigned wbase_u(unsigned w) {
  return 64u * (342u * w - (w * (w - 1u)) / 2u);
}

// Band row index within a staged group: i=word-in-group, d=band distance.
#define BROW(i, d) ((i) == 0 ? 3 + (d) : (i) == 1 ? 7 + (d) \
                    : (i) == 2 ? 12 + (d) : 18 + (d))

// Global base (64 consecutive u64 = one 512B row) for staged row r of group
// gs. r is compile-time under unroll; if-chain folds away.
__device__ __forceinline__ const unsigned long long*
row_gbase(int r, int gs, int W,
          const unsigned long long* diag, const unsigned long long* bandT) {
  if (r < 4) {
    int v = gs * 4 + r; unsigned vc = (v < W) ? (unsigned)v : 0u;
    return diag + ((size_t)vc << 6);
  }
  int i, d;
  if      (r < 8)  { i = 0; d = r - 3;  }
  else if (r < 13) { i = 1; d = r - 7;  }
  else if (r < 19) { i = 2; d = r - 12; }
  else             { i = 3; d = r - 18; }
  int v = gs * 4 + i; unsigned vc = (v < W) ? (unsigned)v : 0u;
  return bandT + (size_t)(d - 1) * NA + ((size_t)vc << 6);
}

// ---------------------------------------------------------------- decode ----
__global__ void decode_kernel(Inputs in,
                              float* __restrict__ dx1, float* __restrict__ dy1,
                              float* __restrict__ dx2, float* __restrict__ dy2,
                              float* __restrict__ dsc,
                              unsigned long long* __restrict__ ckey,
                              unsigned int* __restrict__ Mc,
                              unsigned int* __restrict__ rank32,
                              unsigned int* __restrict__ wcnt,
                              float* __restrict__ out) {
#pragma clang fp contract(off)
  int gid = blockIdx.x * blockDim.x + threadIdx.x;
  if (gid >= N_TOTAL) return;

  rank32[gid] = 0u;
  wcnt[gid] = 0u;
  if (gid < NA - N_TOTAL) wcnt[N_TOTAL + gid] = 0u;

  int sc, local;
  if      (gid < 16384) { sc = 0; local = gid;         }
  else if (gid < 20480) { sc = 1; local = gid - 16384; }
  else if (gid < 21504) { sc = 2; local = gid - 20480; }
  else if (gid < 21760) { sc = 3; local = gid - 21504; }
  else if (gid < 21824) { sc = 4; local = gid - 21760; }
  else                  { sc = 5; local = gid - 21824; }

  const int Wd     = 128 >> sc;
  const int stride = 4 << sc;
  const int HW     = Wd * Wd;
  const int x = local & (Wd - 1);
  const int y = local >> (7 - sc);

  const float* cls = in.cls[sc];
  const float* reg = in.reg[sc];

  float c0 = cls[local];
  float c1 = cls[HW + local];
  float m  = fmaxf(c0, c1);
  float e0 = expf(c0 - m);
  float e1 = expf(c1 - m);
  float prob = e1 / (e0 + e1);

  float l0 = reg[local];
  float l1 = reg[HW + local];
  float l2 = reg[2 * HW + local];
  float l3 = reg[3 * HW + local];

  float sF  = (float)stride;
  float pcx = 0.5f * sF + (float)x * sF;
  float pcy = 0.5f * sF + (float)y * sF;
  float pwh = sF * 4.0f;

  float cx = pcx + ((l0 * 0.1f) * pwh);
  float cy = pcy + ((l1 * 0.1f) * pwh);
  float w  = pwh * expf(l2 * 0.2f);
  float h  = pwh * expf(l3 * 0.2f);
  float x1 = cx - w * 0.5f;
  float y1 = cy - h * 0.5f;
  float x2 = x1 + w;
  float y2 = y1 + h;

  dx1[gid] = x1; dy1[gid] = y1; dx2[gid] = x2; dy2[gid] = y2; dsc[gid] = prob;

  out[gid * 5 + 0] = 0.0f;
  out[gid * 5 + 1] = 0.0f;
  out[gid * 5 + 2] = 0.0f;
  out[gid * 5 + 3] = 0.0f;
  out[gid * 5 + 4] = 0.0f;

  if (prob > FINAL_TH) {
    unsigned int pos = atomicAdd(Mc, 1u);
    ckey[pos] = ((unsigned long long)__float_as_uint(prob) << 32) |
                (unsigned int)(~(unsigned int)gid);
  }
}

// ---------------------------------------------------------------- rank ------
__global__ void __launch_bounds__(256)
rank_kernel(const unsigned long long* __restrict__ ckey,
            const unsigned int* __restrict__ Mc,
            const float* __restrict__ dx1, const float* __restrict__ dy1,
            const float* __restrict__ dx2, const float* __restrict__ dy2,
            float* __restrict__ sx1, float* __restrict__ sy1,
            float* __restrict__ sx2, float* __restrict__ sy2,
            unsigned int* __restrict__ sorig,
            unsigned int* __restrict__ rank32) {
  __shared__ unsigned long long tile[256];
  const unsigned int M = *Mc;
  if (blockIdx.x * 256u >= M) return;          // uniform per block
  const int t = (int)threadIdx.x;
  const int p = (int)blockIdx.x * 256 + t;
  unsigned long long mykey = (p < (int)M) ? ckey[p] : 0ull;
  const int S  = (int)((M + NSLICE - 1) / NSLICE);
  const int lo = (int)blockIdx.y * S;
  const int hi = min((int)M, lo + S);
  int partial = 0;
  const int nt = (hi > lo) ? ((hi - lo + 255) >> 8) : 0;
  for (int ti = 0; ti < nt; ++ti) {
    int j = lo + ti * 256 + t;
    tile[t] = (j < hi) ? ckey[j] : 0ull;       // 0 never > any real key
    __syncthreads();
#pragma unroll 8
    for (int q = 0; q < 256; ++q) partial += (tile[q] > mykey) ? 1 : 0;
    __syncthreads();
  }
  if (p < (int)M) {
    unsigned int pack = (unsigned int)partial | (1u << 24);
    unsigned int old  = atomicAdd(&rank32[p], pack);
    unsigned int newv = old + pack;
    if ((newv >> 24) == NSLICE) {              // last slice to land scatters
      int r = (int)(newv & 0xFFFFFF);
      unsigned int orig = ~(unsigned int)(mykey & 0xffffffffull);
      sx1[r] = dx1[orig];
      sy1[r] = dy1[orig];
      sx2[r] = dx2[orig];
      sy2[r] = dy2[orig];
      sorig[r] = orig;
    }
  }
}

// ---------------------------------------------------------------- pairs -----
// Identical to the verified R6 structure (GRP=4 zones).
__global__ void __launch_bounds__(1024)
pairs_kernel(const float* __restrict__ sx1, const float* __restrict__ sy1,
             const float* __restrict__ sx2, const float* __restrict__ sy2,
             const unsigned int* __restrict__ Mc,
             unsigned long long* __restrict__ diag,
             unsigned long long* __restrict__ bandT,
             unsigned int* __restrict__ wcnt,
             unsigned short* __restrict__ rlMeta,
             unsigned long long* __restrict__ rlBits) {
#pragma clang fp contract(off)
  const int M = (int)*Mc;
  const int W = (M + 63) >> 6;
  const int rw = (int)blockIdx.y;
  const int cwg = (int)blockIdx.x << 4;
  if (rw >= W || cwg >= W || cwg + 22 < rw) return;   // block-uniform

  const int t = (int)threadIdx.x;
  const int g = t >> 6, l = t & 63;
  const int cw = cwg + g;

  __shared__ float cx1[1024], cy1[1024], cx2[1024], cy2[1024], car[1024];
  __shared__ unsigned wvcnt[16], wvbase[16];
  {
    int c = (cw << 6) + l;
    if (cw < W && c < M) {
      float a = sx1[c], b = sy1[c], d = sx2[c], e = sy2[c];
      cx1[t] = a; cy1[t] = b; cx2[t] = d; cy2[t] = e;
      car[t] = (d - a + 1.0f) * (e - b + 1.0f);
    }
  }
  __syncthreads();

  const int rwg = rw >> 2, cg = cw >> 2;
  const bool inW    = (cw < W);
  const bool isDiag = inW && (cw == rw);
  const bool isBand = inW && (cw < rw) && (cg >= rwg - 1);
  const bool isCsr  = inW && (cg >= rwg + 2);
  const bool any    = isDiag || isBand || isCsr;

  const int r = (rw << 6) + l;
  unsigned long long bits = 0ull;
  if (any && r < M) {
    float ax1 = sx1[r], ay1 = sy1[r], ax2 = sx2[r], ay2 = sy2[r];
    float aarea = (ax2 - ax1 + 1.0f) * (ay2 - ay1 + 1.0f);
    const int cmax = min(64, M - (cw << 6));
    const int sb = g << 6;
    for (int cc = 0; cc < cmax; ++cc) {
      float xx1 = fmaxf(ax1, cx1[sb + cc]);
      float yy1 = fmaxf(ay1, cy1[sb + cc]);
      float xx2 = fminf(ax2, cx2[sb + cc]);
      float yy2 = fminf(ay2, cy2[sb + cc]);
      float ww = fmaxf(xx2 - xx1 + 1.0f, 0.0f);
      float hh = fmaxf(yy2 - yy1 + 1.0f, 0.0f);
      float inter = ww * hh;
      float iou = inter / (aarea + car[sb + cc] - inter);
      if (iou > NMS_TH) bits |= (1ull << cc);
    }
  }
  if (isDiag)      diag[r] = bits;
  else if (isBand) bandT[(size_t)(rw - cw - 1) * NA + r] = bits;

  // CSR block-aggregated append
  unsigned long long ball = 0ull;
  unsigned myrank = 0u;
  {
    bool mine = isCsr && (bits != 0ull);
    ball = __ballot(mine);
    myrank = (unsigned)__popcll(ball & ((1ull << l) - 1ull));
    if (l == 0) wvcnt[g] = (unsigned)__popcll(ball);
  }
  __syncthreads();
  if (t == 0) {
    unsigned tot = 0u;
    unsigned pre[16];
#pragma unroll
    for (int i = 0; i < 16; ++i) { pre[i] = tot; tot += wvcnt[i]; }
    unsigned base = (tot != 0u) ? atomicAdd(&wcnt[rw], tot) : 0u;
#pragma unroll
    for (int i = 0; i < 16; ++i) wvbase[i] = base + pre[i];
  }
  __syncthreads();
  if (isCsr && bits != 0ull) {
    unsigned slot = wbase_u((unsigned)rw) + wvbase[g] + myrank;
    rlMeta[slot] = (unsigned short)(((unsigned)l << 9) | (unsigned)cw);
    rlBits[slot] = bits;
  }
}

// ---------------------------------------------------------------- scan ------
// R6 protocol (sflag / per-group gdone, verified) with ONE change: the
// scanner's 26 band/diag values per group arrive via an LDS RING filled by
// width-16 __builtin_amdgcn_global_load_lds (no VGPRs -> immune to the
// register demotion that serialized the loads in R2-R12; R11: per-step cost
// scales with scanner L2 loads consumed in-step: 15/26/100 loads ->
// 2.3/2.3/13.6 µs). Counted s_waitcnt vmcnt(13): group s+1's 13 staging
// loads stay in flight across the whole step (full-step latency hiding).
// Ring-overwrite safety: slot-cur ds_reads complete before the publish
// lgkmcnt(0) memory-clobber, which precedes the slot re-issue.
__global__ void __launch_bounds__(SCAN_T)
scan_kernel(const unsigned long long* __restrict__ diag,
            const unsigned long long* __restrict__ bandT,
            const unsigned int* __restrict__ wcnt,
            const unsigned short* __restrict__ rlMeta,
            const unsigned long long* __restrict__ rlBits,
            const unsigned int* __restrict__ sorig,
            const unsigned int* __restrict__ Mc,
            const float* __restrict__ dx1, const float* __restrict__ dy1,
            const float* __restrict__ dx2, const float* __restrict__ dy2,
            const float* __restrict__ dsc,
            float* __restrict__ out) {
  __shared__ unsigned long long sup[W_MAX];
  __shared__ unsigned long long kmls[W_MAX];
  __shared__ unsigned long long ring[2][NROWS * 64];   // 26.6 KB staging ring
  __shared__ unsigned lds_wcnt[W_MAX];
  __shared__ unsigned gdone[GMAX];
  __shared__ volatile unsigned sflag;
  const int t = (int)threadIdx.x;
  const int g = t >> 6, l = t & 63;
  const int M = (int)*Mc;
  const int W = (M + 63) >> 6;
  const int NS = (W + 3) >> 2;

  for (int i = t; i < W_MAX; i += SCAN_T) {
    sup[i] = 0ull; kmls[i] = 0ull; lds_wcnt[i] = wcnt[i];
  }
  for (int i = t; i < GMAX; i += SCAN_T) gdone[i] = 0u;
  if (t == 0) sflag = 0u;
  block_bar();

  if (g == 0) {
    // -------- scanner wave (critical path) --------
    __builtin_amdgcn_s_setprio(1);
    const unsigned long long lowm = (1ull << l) - 1ull;
    unsigned long long kp[4] = {0ull, 0ull, 0ull, 0ull};

    // Issue 13 width-16 global_load_lds for group gs into ring[sl]:
    // instr j covers rows 2j (lanes 0-31) and 2j+1 (lanes 32-63);
    // per-lane global addr, wave-uniform LDS dest (+lane*16 by HW).
#define STAGE(sl, gs)                                                       \
    { _Pragma("unroll")                                                     \
      for (int j = 0; j < NSTG; ++j) {                                      \
        const unsigned long long* b0 = row_gbase(2 * j,     (gs), W, diag, bandT); \
        const unsigned long long* b1 = row_gbase(2 * j + 1, (gs), W, diag, bandT); \
        const char* gb = (const char*)((l < 32) ? b0 : b1)                  \
                         + (size_t)(l & 31) * 16;                           \
        char* lb = (char*)&ring[(sl)][0] + (size_t)j * 1024;                \
        __builtin_amdgcn_global_load_lds(                                   \
            (const __attribute__((address_space(1))) void*)gb,              \
            (__attribute__((address_space(3))) void*)lb, 16, 0, 0);         \
      } }

    STAGE(0, 0)
    STAGE(1, 1)
    for (int s = 0; s < NS; ++s) {
      const int v0 = s << 2;
      const int cur = s & 1;
      // gate: EVERY pusher wave has applied all source groups <= s-2
      if (s >= 2) {
        while (*(volatile unsigned*)&gdone[s - 2] < (unsigned)NPUSH) {}
        asm volatile("" ::: "memory");
      }
      // slot cur landed (13 newer loads may stay in flight)
      asm volatile("s_waitcnt vmcnt(13)" ::: "memory");
      unsigned long long accp[4];
#pragma unroll
      for (int i = 0; i < 4; ++i) {
        unsigned long long a = 0ull;
#pragma unroll
        for (int d = 1; d <= NBAND; ++d)
          if (d <= i + 4 && d > i)
            a |= (ring[cur][BROW(i, d) * 64 + l] & kp[i - d + 4]);
        accp[i] = a;
      }
      unsigned long long sv[4];
#pragma unroll
      for (int i = 0; i < 4; ++i)
        sv[i] = (v0 + i < W) ? sup[v0 + i] : 0ull;
      unsigned long long kc[4];
#pragma unroll
      for (int i = 0; i < 4; ++i) {
        const int v = v0 + i;
        unsigned long long kept = 0ull;
        if (v < W) {
          unsigned long long acc = accp[i];
#pragma unroll
          for (int d = 1; d <= 3; ++d)
            if (d <= i)
              acc |= (ring[cur][BROW(i, d) * 64 + l] & kc[i - d]);
          unsigned long long incoming = __ballot(acc != 0ull);
          const int n = min(64, M - (v << 6));
          unsigned long long wm = (n >= 64) ? ~0ull : ((1ull << n) - 1ull);
          unsigned long long pend = (~(sv[i] | incoming)) & wm;
          // ballot fixed-point: lowest undecided lane always decides
          const unsigned long long dv = ring[cur][i * 64 + l] & lowm;
          unsigned long long dead = ~pend, und = pend;
          while (und) {
            unsigned long long bS = __ballot((dv & kept) != 0ull) & und;
            unsigned long long bK = __ballot((dv & ~dead) == 0ull) & und;
            kept |= bK; dead |= bS; und &= ~(bK | bS);
          }
          if (l == i) kmls[v] = kept;
        }
        kc[i] = kept;
      }
      // publish group s (kmls + ring reads drained; memory-clobber fence)
      asm volatile("s_waitcnt lgkmcnt(0)" ::: "memory");
      if (l == 0) sflag = (unsigned)(s + 1);
#pragma unroll
      for (int i = 0; i < 4; ++i) kp[i] = kc[i];
      // re-issue this slot for group s+2 (addresses clamped inside)
      STAGE(cur, s + 2)
    }
#undef STAGE
    __builtin_amdgcn_s_setprio(0);
  } else {
    // -------- pusher lanes: dense ranges, static-address depth-2 (R6) -----
    const int p = (g - 1) * 64 + l;              // 0..703

#define PUSH_LOAD(mX, bX, gs)                                               \
    {                                                                       \
      _Pragma("unroll")                                                     \
      for (int i = 0; i < 4; ++i) {                                         \
        int v = (gs) * 4 + i;                                               \
        unsigned vc = (v < W) ? (unsigned)v : 0u;                           \
        unsigned base = wbase_u(vc);                                        \
        unsigned i0 = base + (unsigned)p;   if (i0 >= TOT_ENT) i0 = 0u;     \
        unsigned i1 = i0 + (unsigned)PLANES; if (i1 >= TOT_ENT) i1 = 0u;    \
        mX[i][0] = (unsigned)rlMeta[i0]; bX[i][0] = rlBits[i0];             \
        mX[i][1] = (unsigned)rlMeta[i1]; bX[i][1] = rlBits[i1];             \
      }                                                                     \
    }

    unsigned mA[4][2], mB[4][2];
    unsigned long long bA[4][2], bB[4][2];
    PUSH_LOAD(mA, bA, 0)
    PUSH_LOAD(mB, bB, 1)
    for (int s = 0; s < NS; ++s) {
      while (sflag < (unsigned)(s + 1)) __builtin_amdgcn_s_sleep(1);
      asm volatile("" ::: "memory");
#pragma unroll
      for (int i = 0; i < 4; ++i) {
        const int v = (s << 2) + i;
        if (v < W) {
          const unsigned tw = lds_wcnt[v];
          const unsigned long long km = kmls[v];
          if (km != 0ull && tw != 0u) {
            if ((unsigned)p < tw && ((km >> (mA[i][0] >> 9)) & 1ull))
              atomicOr(&sup[mA[i][0] & 511u], bA[i][0]);
            if ((unsigned)p + (unsigned)PLANES < tw &&
                ((km >> (mA[i][1] >> 9)) & 1ull))
              atomicOr(&sup[mA[i][1] & 511u], bA[i][1]);
            if (tw > 2u * (unsigned)PLANES) {    // rare overflow tail
              unsigned base = wbase_u((unsigned)v);
              for (unsigned ii = (unsigned)p + 2u * (unsigned)PLANES;
                   ii < tw; ii += (unsigned)PLANES) {
                unsigned sl = base + ii; if (sl >= TOT_ENT) sl = TOT_ENT - 1u;
                unsigned mm = (unsigned)rlMeta[sl];
                if ((km >> (mm >> 9)) & 1ull)
                  atomicOr(&sup[mm & 511u], rlBits[sl]);
              }
            }
          }
        }
      }
      asm volatile("s_waitcnt lgkmcnt(0)" ::: "memory");
      if (l == 0) atomicAdd(&gdone[s], 1u);
#pragma unroll
      for (int i = 0; i < 4; ++i) {
        mA[i][0] = mB[i][0]; mA[i][1] = mB[i][1];
        bA[i][0] = bB[i][0]; bA[i][1] = bB[i][1];
      }
      PUSH_LOAD(mB, bB, s + 2)
    }
#undef PUSH_LOAD
  }
  block_bar();

  // scatter kept rows into the (pre-zeroed) output
  for (int i = t; i < (W << 6); i += SCAN_T) {
    if ((kmls[i >> 6] >> (i & 63)) & 1ull) {
      unsigned int orig = sorig[i];
      out[(size_t)orig * 5 + 0] = dx1[orig];
      out[(size_t)orig * 5 + 1] = dy1[orig];
      out[(size_t)orig * 5 + 2] = dx2[orig];
      out[(size_t)orig * 5 + 3] = dy2[orig];
      out[(size_t)orig * 5 + 4] = dsc[orig];
    }
  }
}

// ------------------------------------------------- fallback NMS (tiny ws) ---
__global__ void __launch_bounds__(1024)
nms_kernel(const float* __restrict__ sx1, const float* __restrict__ sy1,
           const float* __restrict__ sx2, const float* __restrict__ sy2,
           const unsigned int* __restrict__ sorig,
           const unsigned int* __restrict__ Mc,
           unsigned int* __restrict__ keepflag) {
#pragma clang fp contract(off)
  __shared__ unsigned long long sup[W_MAX];
  __shared__ unsigned long long inrow[64];
  __shared__ float wx1[64], wy1[64], wx2[64], wy2[64], warea[64];
  __shared__ unsigned long long keptmask_sh;

  const int t = (int)threadIdx.x;
  const int M = (int)*Mc;
  const int W = (M + 63) >> 6;

  for (int i = t; i < W_MAX; i += 1024) sup[i] = 0ull;
  __syncthreads();

  for (int w = 0; w < W; ++w) {
    const int base = w << 6;
    const int n = min(64, M - base);
    if (t < 64) {
      if (t < n) {
        float a = sx1[base + t], b = sy1[base + t];
        float c = sx2[base + t], d = sy2[base + t];
        wx1[t] = a; wy1[t] = b; wx2[t] = c; wy2[t] = d;
        warea[t] = (c - a + 1.0f) * (d - b + 1.0f);
      }
    } else if (t < 128) {
      inrow[t - 64] = 0ull;
    }
    __syncthreads();
    {
      int r = t & 63, seg = t >> 6;
      unsigned long long bits = 0ull;
      if (r < n) {
        float ax1 = wx1[r], ay1 = wy1[r], ax2 = wx2[r], ay2 = wy2[r];
        float aarea = warea[r];
        for (int c = seg * 4; c < seg * 4 + 4; ++c) {
          if (c > r && c < n) {
            float xx1 = fmaxf(ax1, wx1[c]);
            float yy1 = fmaxf(ay1, wy1[c]);
            float xx2 = fminf(ax2, wx2[c]);
            float yy2 = fminf(ay2, wy2[c]);
            float ww = fmaxf(xx2 - xx1 + 1.0f, 0.0f);
            float hh = fmaxf(yy2 - yy1 + 1.0f, 0.0f);
            float inter = ww * hh;
            float iou = inter / (aarea + warea[c] - inter);
            if (iou > NMS_TH) bits |= (1ull << c);
          }
        }
      }
      if (bits) atomicOr(&inrow[r], bits);
    }
    __syncthreads();
    if (t < 64) {
      unsigned long long wordmask = (n >= 64) ? ~0ull : ((1ull << n) - 1ull);
      unsigned long long pending = (~sup[w]) & wordmask;
      unsigned long long kept = 0ull;
      while (pending) {
        int i = __builtin_ctzll(pending);
        kept |= (1ull << i);
        pending &= ~(inrow[i] | (1ull << i));
      }
      if (t == 0) keptmask_sh = kept;
      if (t < n && ((kept >> t) & 1ull)) keepflag[sorig[base + t]] = 1u;
    }
    __syncthreads();
    unsigned long long km = keptmask_sh;
    if (km) {
      int wid = t >> 6, lane = t & 63;
      for (int jw = w + 1 + wid; (jw << 6) < M; jw += 16) {
        int j = (jw << 6) + lane;
        bool supj = false;
        if (j < M) {
          float jx1 = sx1[j], jy1 = sy1[j], jx2 = sx2[j], jy2 = sy2[j];
          float jarea = (jx2 - jx1 + 1.0f) * (jy2 - jy1 + 1.0f);
          unsigned long long mm = km;
          while (mm) {
            int r = __builtin_ctzll(mm);
            mm &= mm - 1ull;
            float xx1 = fmaxf(wx1[r], jx1);
            float yy1 = fmaxf(wy1[r], jy1);
            float xx2 = fminf(wx2[r], jx2);
            float yy2 = fminf(wy2[r], jy2);
            float ww = fmaxf(xx2 - xx1 + 1.0f, 0.0f);
            float hh = fmaxf(yy2 - yy1 + 1.0f, 0.0f);
            float inter = ww * hh;
            float iou = inter / (warea[r] + jarea - inter);
            if (iou > NMS_TH) { supj = true; break; }
          }
        }
        unsigned long long bal = __ballot(supj);
        if (lane == 0 && bal) atomicOr(&sup[jw], bal);
      }
    }
    __syncthreads();
  }
}

// ---------------------------------------------------------------- output ----
// (fallback path only)
__global__ void output_kernel(const float* __restrict__ dx1, const float* __restrict__ dy1,
                              const float* __restrict__ dx2, const float* __restrict__ dy2,
                              const float* __restrict__ dsc,
                              const unsigned int* __restrict__ keepflag,
                              float* __restrict__ out) {
#pragma clang fp contract(off)
  int gid = blockIdx.x * blockDim.x + threadIdx.x;
  if (gid >= N_TOTAL) return;
  float f = keepflag[gid] ? 1.0f : 0.0f;
  out[gid * 5 + 0] = dx1[gid] * f;
  out[gid * 5 + 1] = dy1[gid] * f;
  out[gid * 5 + 2] = dx2[gid] * f;
  out[gid * 5 + 3] = dy2[gid] * f;
  out[gid * 5 + 4] = dsc[gid] * f;
}

// ---------------------------------------------------------------- launch ----
extern "C" void kernel_launch(void* const* d_in, const int* in_sizes, int n_in,
                              void* d_out, int out_size, void* d_ws, size_t ws_size,
                              hipStream_t stream) {
  (void)in_sizes; (void)n_in; (void)out_size;

  Inputs in;
  for (int i = 0; i < 6; ++i) {
    in.cls[i] = (const float*)d_in[2 * i];
    in.reg[i] = (const float*)d_in[2 * i + 1];
  }

  char* ws = (char*)d_ws;
  size_t o = 0;
  float* dx1 = (float*)(ws + o); o += (size_t)NA * 4;
  float* dy1 = (float*)(ws + o); o += (size_t)NA * 4;
  float* dx2 = (float*)(ws + o); o += (size_t)NA * 4;
  float* dy2 = (float*)(ws + o); o += (size_t)NA * 4;
  float* dsc = (float*)(ws + o); o += (size_t)NA * 4;
  unsigned long long* ckey = (unsigned long long*)(ws + o); o += (size_t)NA * 8;
  float* sx1 = (float*)(ws + o); o += (size_t)NA * 4;
  float* sy1 = (float*)(ws + o); o += (size_t)NA * 4;
  float* sx2 = (float*)(ws + o); o += (size_t)NA * 4;
  float* sy2 = (float*)(ws + o); o += (size_t)NA * 4;
  unsigned int* sorig = (unsigned int*)(ws + o); o += (size_t)NA * 4;
  unsigned int* keepflag = (unsigned int*)(ws + o); o += (size_t)NA * 4;
  unsigned int* rank32 = (unsigned int*)(ws + o); o += (size_t)NA * 4;
  unsigned int* wcnt = (unsigned int*)(ws + o); o += (size_t)NA * 4;
  unsigned int* Mc = (unsigned int*)(ws + o); o += 64;
  o = (o + 511) & ~(size_t)511;
  unsigned long long* diag = (unsigned long long*)(ws + o); o += (size_t)NA * 8;
  unsigned long long* bandT = (unsigned long long*)(ws + o); o += (size_t)NBAND * NA * 8;
  unsigned long long* rlBits = (unsigned long long*)(ws + o); o += (size_t)TOT_ENT * 8;
  unsigned short* rlMeta = (unsigned short*)(ws + o); o += (size_t)TOT_ENT * 2;
  size_t need = o;                            // ~41 MiB
  const bool fast = (need <= ws_size);        // ws_size constant -> graph-safe

  const int nb = (N_TOTAL + 255) / 256;  // 86

  if (fast) {
    (void)hipMemsetAsync((void*)Mc, 0, 64, stream);
    decode_kernel<<<nb, 256, 0, stream>>>(in, dx1, dy1, dx2, dy2, dsc, ckey, Mc,
                                          rank32, wcnt, (float*)d_out);
    rank_kernel<<<dim3(nb, NSLICE), 256, 0, stream>>>(ckey, Mc, dx1, dy1, dx2, dy2,
                                                      sx1, sy1, sx2, sy2, sorig,
                                                      rank32);
    pairs_kernel<<<dim3(22, W_MAX), 1024, 0, stream>>>(sx1, sy1, sx2, sy2, Mc,
                                                       diag, bandT, wcnt, rlMeta, rlBits);
    scan_kernel<<<1, SCAN_T, 0, stream>>>(diag, bandT, wcnt, rlMeta, rlBits, sorig, Mc,
                                          dx1, dy1, dx2, dy2, dsc, (float*)d_out);
  } else {
    // fallback: zero keepflag + rank32 + wcnt + Mc (contiguous)
    (void)hipMemsetAsync((void*)keepflag, 0, (size_t)NA * 12 + 64, stream);
    decode_kernel<<<nb, 256, 0, stream>>>(in, dx1, dy1, dx2, dy2, dsc, ckey, Mc,
                                          rank32, wcnt, (float*)d_out);
    rank_kernel<<<dim3(nb, NSLICE), 256, 0, stream>>>(ckey, Mc, dx1, dy1, dx2, dy2,
                                                      sx1, sy1, sx2, sy2, sorig,
                                                      rank32);
    nms_kernel<<<1, 1024, 0, stream>>>(sx1, sy1, sx2, sy2, sorig, Mc, keepflag);
    output_kernel<<<nb, 256, 0, stream>>>(dx1, dy1, dx2, dy2, dsc, keepflag,
                                          (float*)d_out);
  }
}